// Round 10
// baseline (255.815 us; speedup 1.0000x reference)
//
#include <hip/hip_runtime.h>
#include <cstdint>
#include <cstddef>

#define N_NODES  50000
#define N_EDGES  800000
#define DIM      128
#define N_GRAPHS 64
#define NB       98        // coarse buckets of 512 nodes
#define BSH      9
#define EPB      2048      // edges per k_bucket block
#define BPAD     16        // bcur padding: one counter per 64B line

typedef __attribute__((ext_vector_type(8))) short     bf16x8;
typedef __attribute__((ext_vector_type(4))) float     f32x4;

__device__ __forceinline__ int clamp_node(int v) {
    return v < 0 ? 0 : (v >= N_NODES ? N_NODES - 1 : v);
}
__device__ __forceinline__ unsigned short f2bf(float f) {
    union { float f; unsigned u; } v; v.f = f;
    unsigned r = v.u + 0x7FFF + ((v.u >> 16) & 1);   // round-to-nearest-even
    return (unsigned short)(r >> 16);
}
__device__ __forceinline__ float bflo(unsigned u) {
    union { unsigned u; float f; } v; v.u = u << 16; return v.f;
}
__device__ __forceinline__ float bfhi(unsigned u) {
    union { unsigned u; float f; } v; v.u = u & 0xFFFF0000u; return v.f;
}

// ---------------------------------------------------------------------------
// CSR build: histogram of dst, scan. edge_index arrives as int32.
// ---------------------------------------------------------------------------
__global__ void k_hist(const int* __restrict__ ei, int* __restrict__ hist) {
    int e = blockIdx.x * 256 + threadIdx.x;
    if (e < N_EDGES) atomicAdd(&hist[clamp_node(ei[N_EDGES + e])], 1);
}

__global__ void k_blocksum(const int* __restrict__ hist, int* __restrict__ bsum) {
    __shared__ int s[256];
    int base = blockIdx.x * 512;
    int t = threadIdx.x;
    int v = 0;
    if (base + t < N_NODES)       v += hist[base + t];
    if (base + 256 + t < N_NODES) v += hist[base + 256 + t];
    s[t] = v;
    __syncthreads();
    for (int off = 128; off > 0; off >>= 1) {
        if (t < off) s[t] += s[t + off];
        __syncthreads();
    }
    if (t == 0) bsum[blockIdx.x] = s[0];
}

// scan of block sums; also seeds bcur: bucket b's start = rs[b*512] = boff[b].
__global__ void k_scan_bsum(int* bsum, int nb, int* __restrict__ bcur) {
    if (threadIdx.x == 0 && blockIdx.x == 0) {
        int acc = 0;
        for (int i = 0; i < nb; ++i) {
            int v = bsum[i];
            bsum[i] = acc;
            if (i < NB) bcur[i * BPAD] = acc;
            acc += v;
        }
    }
}

// rs[n] = exclusive row start (PRISTINE, never mutated); rs[N]=E. ncur = copy.
__global__ void k_scan_write(const int* __restrict__ hist, const int* __restrict__ boff,
                             int* __restrict__ rs, int* __restrict__ ncur) {
    __shared__ int s[512];
    int t = threadIdx.x;
    int i = blockIdx.x * 512 + t;
    int v = (i < N_NODES) ? hist[i] : 0;
    s[t] = v;
    __syncthreads();
    for (int off = 1; off < 512; off <<= 1) {
        int y = (t >= off) ? s[t - off] : 0;
        __syncthreads();
        s[t] += y;
        __syncthreads();
    }
    int base = boff[blockIdx.x];
    if (i < N_NODES) {
        int st = base + s[t] - v;
        rs[i] = st; ncur[i] = st;
    }
    if (i == N_NODES - 1) rs[N_NODES] = base + s[t];
}

// ---------------------------------------------------------------------------
// Placement phase A: 391 blocks x 2048 edges; LDS counting sort into 98
// coarse buckets; bulk-append runs to global bucket regions. bcur line-padded
// + blockIdx-staggered flush (round-7 lesson: same-line cursor convoy).
// Packed entry: src (16b) | dst_local (9b) << 16.
// ---------------------------------------------------------------------------
__global__ __launch_bounds__(512) void k_bucket(const int* __restrict__ ei,
                                                int* __restrict__ bcur,
                                                unsigned* __restrict__ tmp) {
    __shared__ int cnt[128], cur[128], ofs[128];
    __shared__ int s[512];
    __shared__ unsigned list[EPB];
    int t = threadIdx.x;
    int base = blockIdx.x * EPB;
    int eend = base + EPB; if (eend > N_EDGES) eend = N_EDGES;

    if (t < 128) cnt[t] = 0;
    __syncthreads();

    int d[4], sv[4];
    bool ok[4];
    #pragma unroll
    for (int i = 0; i < 4; ++i) {
        int e = base + t + i * 512;
        ok[i] = (e < eend);
        if (ok[i]) {
            d[i]  = clamp_node(ei[N_EDGES + e]);
            sv[i] = clamp_node(ei[e]);
            atomicAdd(&cnt[d[i] >> BSH], 1);
        }
    }
    __syncthreads();
    int v = (t < 128) ? cnt[t] : 0;
    s[t] = v;
    __syncthreads();
    for (int off = 1; off < 128; off <<= 1) {
        int y = (t >= off && t < 128) ? s[t - off] : 0;
        __syncthreads();
        if (t < 128) s[t] += y;
        __syncthreads();
    }
    if (t < 128) { ofs[t] = s[t] - v; cur[t] = s[t] - v; }
    __syncthreads();
    #pragma unroll
    for (int i = 0; i < 4; ++i) {
        if (ok[i]) {
            int b = d[i] >> BSH;
            int p = atomicAdd(&cur[b], 1);
            list[p] = (unsigned)sv[i] | ((unsigned)(d[i] & 511) << 16);
        }
    }
    __syncthreads();
    int wv = t >> 6, lane = t & 63;
    const int NGRP = 13;   // ceil(98/8)
    for (int jj = 0; jj < NGRP; ++jj) {
        int b = wv + 8 * ((jj + (int)blockIdx.x) % NGRP);
        if (b >= NB) continue;
        int c = cnt[b];
        if (c == 0) continue;
        int gpos;
        if (lane == 0) gpos = atomicAdd(&bcur[b * BPAD], c);
        gpos = __shfl(gpos, 0);
        int ls = ofs[b];
        for (int i = lane; i < c; i += 64) tmp[gpos + i] = list[ls + i];
    }
}

// ---------------------------------------------------------------------------
// Placement phase B: one block per bucket; scatter confined to the
// block-exclusive 32KB srcs region (full-line evicts).
// ---------------------------------------------------------------------------
__global__ __launch_bounds__(512) void k_place2(const unsigned* __restrict__ tmp,
                                                const int* __restrict__ rs,
                                                int* __restrict__ ncur,
                                                int* __restrict__ srcs) {
    int b   = blockIdx.x;
    int nlo = b << BSH;
    int nhi = nlo + 512; if (nhi > N_NODES) nhi = N_NODES;
    int estart = rs[nlo], eend = rs[nhi];
    for (int e = estart + (int)threadIdx.x; e < eend; e += 512) {
        unsigned val = tmp[e];
        int d = nlo + (int)(val >> 16);
        int pos = atomicAdd(&ncur[d], 1);
        srcs[pos] = (int)(val & 0xFFFFu);
    }
}

// ---------------------------------------------------------------------------
// f32 -> bf16 convert into PLANE-SPLIT layout:
// plane c (c=dim>>5) holds node-major 32-dim (64B) chunks:
//   xb[((c*N + node)*32) + (dim & 31)]
// Thread i handles node i>>4, part i&15 (8 dims).
// ---------------------------------------------------------------------------
__global__ __launch_bounds__(256) void k_tobf16p(const float* __restrict__ in,
                                                 unsigned short* __restrict__ outp) {
    int i = blockIdx.x * 256 + threadIdx.x;
    if (i >= N_NODES * 16) return;
    int node = i >> 4, part = i & 15;
    const float4* p = (const float4*)(in + (size_t)node * DIM + part * 8);
    float4 a = p[0], b = p[1];
    union { unsigned short s[8]; uint4 u; } o;
    o.s[0] = f2bf(a.x); o.s[1] = f2bf(a.y); o.s[2] = f2bf(a.z); o.s[3] = f2bf(a.w);
    o.s[4] = f2bf(b.x); o.s[5] = f2bf(b.y); o.s[6] = f2bf(b.z); o.s[7] = f2bf(b.w);
    *(uint4*)(outp + ((size_t)(part >> 2) * N_NODES + node) * 32 + (part & 3) * 8) = o.u;
}

// ---------------------------------------------------------------------------
// Pack BOTH concat weights [Wl;Wr]^T into MFMA fragment order (one launch).
// frag[(ot*8+ks)*64 + lane][j] = B[ks*32 + (lane>>4)*8 + j][ot*16 + (lane&15)]
// ---------------------------------------------------------------------------
__global__ void k_wprep2(const float* __restrict__ W1l, const float* __restrict__ W1r,
                         const float* __restrict__ W2l, const float* __restrict__ W2r,
                         unsigned short* __restrict__ wbuf1,
                         unsigned short* __restrict__ wbuf2) {
    int tid = blockIdx.x * 256 + threadIdx.x;
    if (tid >= 2 * 8 * 8 * 64) return;
    int which = tid >> 12;
    int id    = tid & 4095;
    const float* Wl = which ? W2l : W1l;
    const float* Wr = which ? W2r : W1r;
    unsigned short* wbuf = which ? wbuf2 : wbuf1;
    int lane = id & 63;
    int ks   = (id >> 6) & 7;
    int ot   = id >> 9;
    int o  = ot * 16 + (lane & 15);
    int kb = ks * 32 + ((lane >> 4) << 3);
    union { unsigned short s[8]; uint4 u; } frag;
    #pragma unroll
    for (int j = 0; j < 8; ++j) {
        int k = kb + j;
        float v = (k < DIM) ? Wl[o * DIM + k] : Wr[o * DIM + (k - DIM)];
        frag.s[j] = f2bf(v);
    }
    *(uint4*)(wbuf + (size_t)id * 8) = frag.u;
}

// ---------------------------------------------------------------------------
// FUSED SAGE layer, L2-resident chunked gather (plane-split feat/in2/out):
// 4 dim-chunk passes; pass c touches only plane c (3.2MB < 4MB XCD L2).
// Wave lane = (q=node[2b], es=edge-slot[2b], sub=16B-chunk[2b]).
// Per pass: accumulate 8 f32/lane over es-strided edges, 2x shfl_xor reduce
// over es, es==0 lanes write bf16 mean to LDS. Then MFMA dual-GEMM+bias+ReLU.
// ---------------------------------------------------------------------------
__global__ __launch_bounds__(256) void k_sage(const unsigned short* __restrict__ feat,
                                              const unsigned short* __restrict__ in2b,
                                              const int* __restrict__ rs,
                                              const int* __restrict__ srcs,
                                              const unsigned short* __restrict__ wbuf,
                                              const float* __restrict__ bias,
                                              unsigned short* __restrict__ outb) {
    __shared__ unsigned short almp[16][136];
    int t    = threadIdx.x;
    int wave = t >> 6;
    int lane = t & 63;
    int n0   = blockIdx.x * 16;

    // B fragments first (independent; hide under gather)
    bf16x8 B[2][8];
    #pragma unroll
    for (int ot = 0; ot < 2; ++ot)
        #pragma unroll
        for (int ks = 0; ks < 8; ++ks)
            B[ot][ks] = *(const bf16x8*)(wbuf +
                (((size_t)(wave * 2 + ot) * 8 + ks) * 64 + lane) * 8);

    // ---- phase 1: chunked gather-mean ----
    {
        int q   = lane >> 4;
        int es  = (lane >> 2) & 3;
        int sub = lane & 3;
        int node  = n0 + wave * 4 + q;
        int start = rs[node];
        int end   = rs[node + 1];
        float inv = 1.0f / fmaxf((float)(end - start), 1.0f);
        const size_t soff = (size_t)sub * 8;

#define ACC8(r) { a0 += bflo(r.x); a1 += bfhi(r.x); a2 += bflo(r.y); a3 += bfhi(r.y); \
                  a4 += bflo(r.z); a5 += bfhi(r.z); a6 += bflo(r.w); a7 += bfhi(r.w); }
        #pragma unroll
        for (int c = 0; c < 4; ++c) {
            const unsigned short* plane = feat + (size_t)c * N_NODES * 32;
            float a0 = 0.f, a1 = 0.f, a2 = 0.f, a3 = 0.f;
            float a4 = 0.f, a5 = 0.f, a6 = 0.f, a7 = 0.f;
            int e = start + es;
            for (; e + 4 < end; e += 8) {
                uint4 r0 = *(const uint4*)(plane + (size_t)srcs[e]     * 32 + soff);
                uint4 r1 = *(const uint4*)(plane + (size_t)srcs[e + 4] * 32 + soff);
                ACC8(r0) ACC8(r1)
            }
            if (e < end) {
                uint4 r0 = *(const uint4*)(plane + (size_t)srcs[e] * 32 + soff);
                ACC8(r0)
            }
            // reduce over es (lane bits 2..3)
            a0 += __shfl_xor(a0, 4); a1 += __shfl_xor(a1, 4);
            a2 += __shfl_xor(a2, 4); a3 += __shfl_xor(a3, 4);
            a4 += __shfl_xor(a4, 4); a5 += __shfl_xor(a5, 4);
            a6 += __shfl_xor(a6, 4); a7 += __shfl_xor(a7, 4);
            a0 += __shfl_xor(a0, 8); a1 += __shfl_xor(a1, 8);
            a2 += __shfl_xor(a2, 8); a3 += __shfl_xor(a3, 8);
            a4 += __shfl_xor(a4, 8); a5 += __shfl_xor(a5, 8);
            a6 += __shfl_xor(a6, 8); a7 += __shfl_xor(a7, 8);
            if (es == 0) {
                union { unsigned short s[8]; uint4 u; } o;
                o.s[0] = f2bf(a0 * inv); o.s[1] = f2bf(a1 * inv);
                o.s[2] = f2bf(a2 * inv); o.s[3] = f2bf(a3 * inv);
                o.s[4] = f2bf(a4 * inv); o.s[5] = f2bf(a5 * inv);
                o.s[6] = f2bf(a6 * inv); o.s[7] = f2bf(a7 * inv);
                *(uint4*)&almp[wave * 4 + q][c * 32 + sub * 8] = o.u;
            }
        }
#undef ACC8
    }
    __syncthreads();

    // ---- phase 2: MFMA ----
    int row = lane & 15;
    int kg  = lane >> 4;            // k-group 0..3, 8 dims each
    bf16x8 A[8];
    #pragma unroll
    for (int ks = 0; ks < 4; ++ks)
        A[ks] = *(const bf16x8*)&almp[row][ks * 32 + kg * 8];
    #pragma unroll
    for (int ks = 0; ks < 4; ++ks)
        A[4 + ks] = *(const bf16x8*)(in2b +
            ((size_t)ks * N_NODES + n0 + row) * 32 + kg * 8);

    f32x4 acc0 = {0.f, 0.f, 0.f, 0.f}, acc1 = {0.f, 0.f, 0.f, 0.f};
    #pragma unroll
    for (int ks = 0; ks < 8; ++ks) {
        acc0 = __builtin_amdgcn_mfma_f32_16x16x32_bf16(A[ks], B[0][ks], acc0, 0, 0, 0);
        acc1 = __builtin_amdgcn_mfma_f32_16x16x32_bf16(A[ks], B[1][ks], acc1, 0, 0, 0);
    }

    // C/D layout: col = lane&15, row = (lane>>4)*4 + reg   [m89-verified]
    // Output dims [wave*32, wave*32+32) == plane `wave`, local dim ocol / ocol+16.
    int ocol = lane & 15;
    int rb   = kg << 2;
    float b0 = bias[wave * 32 + ocol];
    float b1 = bias[wave * 32 + 16 + ocol];
    unsigned short* oplane = outb + (size_t)wave * N_NODES * 32;
    #pragma unroll
    for (int r = 0; r < 4; ++r) {
        size_t n = (size_t)(n0 + rb + r);
        oplane[n * 32 + ocol]      = f2bf(fmaxf(acc0[r] + b0, 0.f));
        oplane[n * 32 + 16 + ocol] = f2bf(fmaxf(acc1[r] + b1, 0.f));
    }
}

// ---------------------------------------------------------------------------
// Pool stage 1: partial per-graph sums (batch sorted; flush on graph change).
// h2 is plane-split: dims (2l,2l+1) -> plane l>>4, local (2l)&31.
// ---------------------------------------------------------------------------
__global__ __launch_bounds__(256) void k_pool_partial(const unsigned short* __restrict__ h2,
                                                      const int* __restrict__ batch,
                                                      float* __restrict__ gsum) {
    int wid  = (blockIdx.x * 256 + threadIdx.x) >> 6;
    int lane = threadIdx.x & 63;
    int n0 = wid * 32;
    if (n0 >= N_NODES) return;
    int n1 = n0 + 32; if (n1 > N_NODES) n1 = N_NODES;
    int col = lane * 2;
    const unsigned short* plane = h2 + (size_t)(lane >> 4) * N_NODES * 32;
    int loc = col & 31;

    float ax = 0.f, ay = 0.f;
    int cur = batch[n0];
    for (int n = n0; n < n1; ++n) {
        int b = batch[n];
        if (b != cur) {
            atomicAdd(&gsum[cur * DIM + col], ax);
            atomicAdd(&gsum[cur * DIM + col + 1], ay);
            ax = 0.f; ay = 0.f; cur = b;
        }
        unsigned u = *(const unsigned*)(plane + (size_t)n * 32 + loc);
        ax += bflo(u); ay += bfhi(u);
    }
    atomicAdd(&gsum[cur * DIM + col], ax);
    atomicAdd(&gsum[cur * DIM + col + 1], ay);
}

// ---------------------------------------------------------------------------
// Pool stage 2: mean + MLP head. One block per graph.
// ---------------------------------------------------------------------------
__global__ __launch_bounds__(256) void k_head(const float* __restrict__ gsum,
                                              const int* __restrict__ batch,
                                              const float* __restrict__ wl1,
                                              const float* __restrict__ bl1,
                                              const float* __restrict__ wout,
                                              const float* __restrict__ bout,
                                              float* __restrict__ out) {
    int g = blockIdx.x;
    int t = threadIdx.x;

    int lo = 0, hi = N_NODES;
    while (lo < hi) { int mid = (lo + hi) >> 1; if (batch[mid] < g) lo = mid + 1; else hi = mid; }
    int s = lo;
    lo = 0; hi = N_NODES;
    while (lo < hi) { int mid = (lo + hi) >> 1; if (batch[mid] < g + 1) lo = mid + 1; else hi = mid; }
    int e = lo;

    __shared__ float gvec[DIM];
    if (t < DIM) {
        float cnt = fmaxf((float)(e - s), 1.0f);
        gvec[t] = gsum[g * DIM + t] / cnt;
    }
    __syncthreads();
    if (t < 64) {
        float a = bl1[t];
        #pragma unroll 4
        for (int k = 0; k < DIM; ++k) a += wl1[t * DIM + k] * gvec[k];
        float g1 = fmaxf(a, 0.f) * wout[t];
        #pragma unroll
        for (int off = 32; off > 0; off >>= 1) g1 += __shfl_down(g1, off);
        if (t == 0) {
            float z = g1 + bout[0];
            out[g] = 1.0f / (1.0f + expf(-z));
        }
    }
}

// ---------------------------------------------------------------------------
extern "C" void kernel_launch(void* const* d_in, const int* in_sizes, int n_in,
                              void* d_out, int out_size, void* d_ws, size_t ws_size,
                              hipStream_t stream) {
    const float* x     = (const float*)d_in[0];
    const int*   ei    = (const int*)d_in[1];    // int64 in ref -> int32 here
    const int*   batch = (const int*)d_in[2];
    const float* w1l   = (const float*)d_in[3];
    const float* b1l   = (const float*)d_in[4];
    const float* w1r   = (const float*)d_in[5];
    const float* w2l   = (const float*)d_in[6];
    const float* b2l   = (const float*)d_in[7];
    const float* w2r   = (const float*)d_in[8];
    const float* wl1   = (const float*)d_in[9];
    const float* bl1   = (const float*)d_in[10];
    const float* wout  = (const float*)d_in[11];
    const float* bout  = (const float*)d_in[12];
    float* out = (float*)d_out;

    char*  wsp = (char*)d_ws;
    size_t off = 0;
    auto alloc = [&](size_t bytes) -> char* {
        char* p = wsp + off;
        off += (bytes + 255) & ~(size_t)255;
        return p;
    };
    int* rs   = (int*)alloc((size_t)(N_NODES + 1) * 4);
    int* ncur = (int*)alloc((size_t)N_NODES * 4);
    int* hist = (int*)alloc((size_t)N_NODES * 4);
    int* bsum = (int*)alloc(256 * 4);
    int* bcur = (int*)alloc((size_t)NB * BPAD * 4);
    int* srcs = (int*)alloc((size_t)N_EDGES * 4);
    unsigned* tmp = (unsigned*)alloc((size_t)N_EDGES * 4);
    unsigned short* xb    = (unsigned short*)alloc((size_t)N_NODES * DIM * 2);
    unsigned short* h1b   = (unsigned short*)alloc((size_t)N_NODES * DIM * 2);
    unsigned short* h2b   = (unsigned short*)alloc((size_t)N_NODES * DIM * 2);
    unsigned short* wbuf1 = (unsigned short*)alloc((size_t)8 * 8 * 64 * 8 * 2);
    unsigned short* wbuf2 = (unsigned short*)alloc((size_t)8 * 8 * 64 * 8 * 2);
    float* gsum = (float*)alloc((size_t)N_GRAPHS * DIM * 4);

    const int nb = (N_NODES + 511) / 512;   // 98

    hipMemsetAsync(hist, 0, (size_t)N_NODES * 4, stream);
    hipMemsetAsync(gsum, 0, (size_t)N_GRAPHS * DIM * 4, stream);
    k_hist<<<(N_EDGES + 255) / 256, 256, 0, stream>>>(ei, hist);
    k_blocksum<<<nb, 256, 0, stream>>>(hist, bsum);
    k_scan_bsum<<<1, 64, 0, stream>>>(bsum, nb, bcur);
    k_scan_write<<<nb, 512, 0, stream>>>(hist, bsum, rs, ncur);
    k_bucket<<<(N_EDGES + EPB - 1) / EPB, 512, 0, stream>>>(ei, bcur, tmp);
    k_place2<<<NB, 512, 0, stream>>>(tmp, rs, ncur, srcs);

    // dtype prep (plane-split layout)
    k_tobf16p<<<(N_NODES * 16 + 255) / 256, 256, 0, stream>>>(x, xb);
    k_wprep2<<<32, 256, 0, stream>>>(w1l, w1r, w2l, w2r, wbuf1, wbuf2);

    // conv1 (fused aggregate + GEMM, chunked gather)
    k_sage<<<N_NODES / 16, 256, 0, stream>>>(xb, xb, rs, srcs, wbuf1, b1l, h1b);
    // conv2
    k_sage<<<N_NODES / 16, 256, 0, stream>>>(h1b, h1b, rs, srcs, wbuf2, b2l, h2b);
    // pool (2-stage) + head
    k_pool_partial<<<(N_NODES + 127) / 128, 256, 0, stream>>>(h2b, batch, gsum);
    k_head<<<N_GRAPHS, 256, 0, stream>>>(gsum, batch, wl1, bl1, wout, bout, out);
}

// Round 11
// 236.158 us; speedup vs baseline: 1.0832x; 1.0832x over previous
//
#include <hip/hip_runtime.h>
#include <cstdint>
#include <cstddef>

#define N_NODES  50000
#define N_EDGES  800000
#define DIM      128
#define N_GRAPHS 64
#define NB       98        // coarse buckets of 512 nodes
#define BSH      9
#define EPB      2048      // edges per k_bucket block
#define BPAD     16        // bcur padding: one counter per 64B line

typedef __attribute__((ext_vector_type(8))) short     bf16x8;
typedef __attribute__((ext_vector_type(4))) float     f32x4;

__device__ __forceinline__ int clamp_node(int v) {
    return v < 0 ? 0 : (v >= N_NODES ? N_NODES - 1 : v);
}
__device__ __forceinline__ unsigned short f2bf(float f) {
    union { float f; unsigned u; } v; v.f = f;
    unsigned r = v.u + 0x7FFF + ((v.u >> 16) & 1);   // round-to-nearest-even
    return (unsigned short)(r >> 16);
}
__device__ __forceinline__ float bflo(unsigned u) {
    union { unsigned u; float f; } v; v.u = u << 16; return v.f;
}
__device__ __forceinline__ float bfhi(unsigned u) {
    union { unsigned u; float f; } v; v.u = u & 0xFFFF0000u; return v.f;
}

// ---------------------------------------------------------------------------
// CSR build: histogram of dst, scan. edge_index arrives as int32.
// ---------------------------------------------------------------------------
__global__ void k_hist(const int* __restrict__ ei, int* __restrict__ hist) {
    int e = blockIdx.x * 256 + threadIdx.x;
    if (e < N_EDGES) atomicAdd(&hist[clamp_node(ei[N_EDGES + e])], 1);
}

__global__ void k_blocksum(const int* __restrict__ hist, int* __restrict__ bsum) {
    __shared__ int s[256];
    int base = blockIdx.x * 512;
    int t = threadIdx.x;
    int v = 0;
    if (base + t < N_NODES)       v += hist[base + t];
    if (base + 256 + t < N_NODES) v += hist[base + 256 + t];
    s[t] = v;
    __syncthreads();
    for (int off = 128; off > 0; off >>= 1) {
        if (t < off) s[t] += s[t + off];
        __syncthreads();
    }
    if (t == 0) bsum[blockIdx.x] = s[0];
}

// scan of block sums; also seeds bcur: bucket b's start = rs[b*512] = boff[b].
__global__ void k_scan_bsum(int* bsum, int nb, int* __restrict__ bcur) {
    if (threadIdx.x == 0 && blockIdx.x == 0) {
        int acc = 0;
        for (int i = 0; i < nb; ++i) {
            int v = bsum[i];
            bsum[i] = acc;
            if (i < NB) bcur[i * BPAD] = acc;
            acc += v;
        }
    }
}

// rs[n] = exclusive row start (PRISTINE, never mutated); rs[N]=E. ncur = copy.
__global__ void k_scan_write(const int* __restrict__ hist, const int* __restrict__ boff,
                             int* __restrict__ rs, int* __restrict__ ncur) {
    __shared__ int s[512];
    int t = threadIdx.x;
    int i = blockIdx.x * 512 + t;
    int v = (i < N_NODES) ? hist[i] : 0;
    s[t] = v;
    __syncthreads();
    for (int off = 1; off < 512; off <<= 1) {
        int y = (t >= off) ? s[t - off] : 0;
        __syncthreads();
        s[t] += y;
        __syncthreads();
    }
    int base = boff[blockIdx.x];
    if (i < N_NODES) {
        int st = base + s[t] - v;
        rs[i] = st; ncur[i] = st;
    }
    if (i == N_NODES - 1) rs[N_NODES] = base + s[t];
}

// ---------------------------------------------------------------------------
// Placement phase A: 391 blocks x 2048 edges; LDS counting sort into 98
// coarse buckets; bulk-append runs to global bucket regions. bcur line-padded
// + blockIdx-staggered flush (round-7 lesson: same-line cursor convoy).
// Packed entry: src (16b) | dst_local (9b) << 16.
// ---------------------------------------------------------------------------
__global__ __launch_bounds__(512) void k_bucket(const int* __restrict__ ei,
                                                int* __restrict__ bcur,
                                                unsigned* __restrict__ tmp) {
    __shared__ int cnt[128], cur[128], ofs[128];
    __shared__ int s[512];
    __shared__ unsigned list[EPB];
    int t = threadIdx.x;
    int base = blockIdx.x * EPB;
    int eend = base + EPB; if (eend > N_EDGES) eend = N_EDGES;

    if (t < 128) cnt[t] = 0;
    __syncthreads();

    int d[4], sv[4];
    bool ok[4];
    #pragma unroll
    for (int i = 0; i < 4; ++i) {
        int e = base + t + i * 512;
        ok[i] = (e < eend);
        if (ok[i]) {
            d[i]  = clamp_node(ei[N_EDGES + e]);
            sv[i] = clamp_node(ei[e]);
            atomicAdd(&cnt[d[i] >> BSH], 1);
        }
    }
    __syncthreads();
    int v = (t < 128) ? cnt[t] : 0;
    s[t] = v;
    __syncthreads();
    for (int off = 1; off < 128; off <<= 1) {
        int y = (t >= off && t < 128) ? s[t - off] : 0;
        __syncthreads();
        if (t < 128) s[t] += y;
        __syncthreads();
    }
    if (t < 128) { ofs[t] = s[t] - v; cur[t] = s[t] - v; }
    __syncthreads();
    #pragma unroll
    for (int i = 0; i < 4; ++i) {
        if (ok[i]) {
            int b = d[i] >> BSH;
            int p = atomicAdd(&cur[b], 1);
            list[p] = (unsigned)sv[i] | ((unsigned)(d[i] & 511) << 16);
        }
    }
    __syncthreads();
    int wv = t >> 6, lane = t & 63;
    const int NGRP = 13;   // ceil(98/8)
    for (int jj = 0; jj < NGRP; ++jj) {
        int b = wv + 8 * ((jj + (int)blockIdx.x) % NGRP);
        if (b >= NB) continue;
        int c = cnt[b];
        if (c == 0) continue;
        int gpos;
        if (lane == 0) gpos = atomicAdd(&bcur[b * BPAD], c);
        gpos = __shfl(gpos, 0);
        int ls = ofs[b];
        for (int i = lane; i < c; i += 64) tmp[gpos + i] = list[ls + i];
    }
}

// ---------------------------------------------------------------------------
// Placement phase B: one block per bucket; scatter confined to the
// block-exclusive 32KB srcs region (full-line evicts).
// ---------------------------------------------------------------------------
__global__ __launch_bounds__(512) void k_place2(const unsigned* __restrict__ tmp,
                                                const int* __restrict__ rs,
                                                int* __restrict__ ncur,
                                                int* __restrict__ srcs) {
    int b   = blockIdx.x;
    int nlo = b << BSH;
    int nhi = nlo + 512; if (nhi > N_NODES) nhi = N_NODES;
    int estart = rs[nlo], eend = rs[nhi];
    for (int e = estart + (int)threadIdx.x; e < eend; e += 512) {
        unsigned val = tmp[e];
        int d = nlo + (int)(val >> 16);
        int pos = atomicAdd(&ncur[d], 1);
        srcs[pos] = (int)(val & 0xFFFFu);
    }
}

// ---------------------------------------------------------------------------
// Prep (one launch): f32->bf16 row-major feature convert + pack both concat
// weights [Wl;Wr]^T into MFMA fragment order.
// frag[(ot*8+ks)*64 + lane][j] = B[ks*32 + (lane>>4)*8 + j][ot*16 + (lane&15)]
// ---------------------------------------------------------------------------
__global__ __launch_bounds__(256) void k_prep(const float* __restrict__ x,
                                              unsigned short* __restrict__ xb,
                                              const float* __restrict__ W1l,
                                              const float* __restrict__ W1r,
                                              const float* __restrict__ W2l,
                                              const float* __restrict__ W2r,
                                              unsigned short* __restrict__ wbuf1,
                                              unsigned short* __restrict__ wbuf2) {
    int i = blockIdx.x * 256 + threadIdx.x;
    const int n8 = N_NODES * 16;            // 800000 8-elem conversions
    if (i < n8) {
        const float4* p = (const float4*)(x + (size_t)i * 8);
        float4 a = p[0], b = p[1];
        union { unsigned short s[8]; uint4 u; } o;
        o.s[0] = f2bf(a.x); o.s[1] = f2bf(a.y); o.s[2] = f2bf(a.z); o.s[3] = f2bf(a.w);
        o.s[4] = f2bf(b.x); o.s[5] = f2bf(b.y); o.s[6] = f2bf(b.z); o.s[7] = f2bf(b.w);
        *(uint4*)(xb + (size_t)i * 8) = o.u;
        return;
    }
    int tid = i - n8;
    if (tid >= 2 * 8 * 8 * 64) return;
    int which = tid >> 12;
    int id    = tid & 4095;
    const float* Wl = which ? W2l : W1l;
    const float* Wr = which ? W2r : W1r;
    unsigned short* wbuf = which ? wbuf2 : wbuf1;
    int lane = id & 63;
    int ks   = (id >> 6) & 7;
    int ot   = id >> 9;
    int o  = ot * 16 + (lane & 15);
    int kb = ks * 32 + ((lane >> 4) << 3);
    union { unsigned short s[8]; uint4 u; } frag;
    #pragma unroll
    for (int j = 0; j < 8; ++j) {
        int k = kb + j;
        float v = (k < DIM) ? Wl[o * DIM + k] : Wr[o * DIM + (k - DIM)];
        frag.s[j] = f2bf(v);
    }
    *(uint4*)(wbuf + (size_t)id * 8) = frag.u;
}

// ---------------------------------------------------------------------------
// FUSED SAGE layer (round-9 structure; row-major feat): gather-mean
// (4 nodes/wave, 8x unroll, 32 rows outstanding/wave) -> LDS tile -> MFMA
// dual-GEMM + bias + ReLU -> bf16 store. Block = 4 waves = 16 nodes.
// B-fragments AND root A-fragments are loaded BEFORE the gather so their
// latency hides under it (root frags were post-barrier in round 9).
// Round-10 lesson: per-block dim-chunking desyncs across blocks -> per-XCD
// working set stays 12.8MB AND per-lane MLP drops 4x. Don't chunk.
// ---------------------------------------------------------------------------
__global__ __launch_bounds__(256) void k_sage(const unsigned short* __restrict__ feat,
                                              const unsigned short* __restrict__ in2b,
                                              const int* __restrict__ rs,
                                              const int* __restrict__ srcs,
                                              const unsigned short* __restrict__ wbuf,
                                              const float* __restrict__ bias,
                                              unsigned short* __restrict__ outb) {
    __shared__ unsigned short almp[16][136];   // row stride 272B
    int t    = threadIdx.x;
    int wave = t >> 6;
    int lane = t & 63;
    int n0   = blockIdx.x * 16;

    // B fragments first (independent; hide under gather)
    bf16x8 B[2][8];
    #pragma unroll
    for (int ot = 0; ot < 2; ++ot)
        #pragma unroll
        for (int ks = 0; ks < 8; ++ks)
            B[ot][ks] = *(const bf16x8*)(wbuf +
                (((size_t)(wave * 2 + ot) * 8 + ks) * 64 + lane) * 8);

    // Root A-fragments preloaded too (consumed after the barrier)
    bf16x8 A[8];
    {
        const unsigned short* xrow = in2b +
            (size_t)(n0 + (lane & 15)) * DIM + ((lane >> 4) << 3);
        #pragma unroll
        for (int ks = 0; ks < 4; ++ks)
            A[4 + ks] = *(const bf16x8*)(xrow + ks * 32);
    }

    // ---- phase 1: gather-mean; lane (q,sub) owns node q's 16B chunk sub ----
    {
        int q   = lane >> 4;
        int sub = lane & 15;
        int node  = n0 + wave * 4 + q;
        int start = rs[node];
        int end   = rs[node + 1];
        float a0 = 0.f, a1 = 0.f, a2 = 0.f, a3 = 0.f;
        float a4 = 0.f, a5 = 0.f, a6 = 0.f, a7 = 0.f;
        const size_t coff = (size_t)sub * 8;

#define ACC8(r) { a0 += bflo(r.x); a1 += bfhi(r.x); a2 += bflo(r.y); a3 += bfhi(r.y); \
                  a4 += bflo(r.z); a5 += bfhi(r.z); a6 += bflo(r.w); a7 += bfhi(r.w); }
        int e = start;
        for (; e + 8 <= end; e += 8) {
            uint4 r0 = *(const uint4*)(feat + (size_t)srcs[e + 0] * DIM + coff);
            uint4 r1 = *(const uint4*)(feat + (size_t)srcs[e + 1] * DIM + coff);
            uint4 r2 = *(const uint4*)(feat + (size_t)srcs[e + 2] * DIM + coff);
            uint4 r3 = *(const uint4*)(feat + (size_t)srcs[e + 3] * DIM + coff);
            uint4 r4 = *(const uint4*)(feat + (size_t)srcs[e + 4] * DIM + coff);
            uint4 r5 = *(const uint4*)(feat + (size_t)srcs[e + 5] * DIM + coff);
            uint4 r6 = *(const uint4*)(feat + (size_t)srcs[e + 6] * DIM + coff);
            uint4 r7 = *(const uint4*)(feat + (size_t)srcs[e + 7] * DIM + coff);
            ACC8(r0) ACC8(r1) ACC8(r2) ACC8(r3) ACC8(r4) ACC8(r5) ACC8(r6) ACC8(r7)
        }
        for (; e + 2 <= end; e += 2) {
            uint4 r0 = *(const uint4*)(feat + (size_t)srcs[e + 0] * DIM + coff);
            uint4 r1 = *(const uint4*)(feat + (size_t)srcs[e + 1] * DIM + coff);
            ACC8(r0) ACC8(r1)
        }
        if (e < end) {
            uint4 r0 = *(const uint4*)(feat + (size_t)srcs[e] * DIM + coff);
            ACC8(r0)
        }
#undef ACC8
        float inv = 1.0f / fmaxf((float)(end - start), 1.0f);
        union { unsigned short s[8]; uint4 u; } o;
        o.s[0] = f2bf(a0 * inv); o.s[1] = f2bf(a1 * inv);
        o.s[2] = f2bf(a2 * inv); o.s[3] = f2bf(a3 * inv);
        o.s[4] = f2bf(a4 * inv); o.s[5] = f2bf(a5 * inv);
        o.s[6] = f2bf(a6 * inv); o.s[7] = f2bf(a7 * inv);
        *(uint4*)&almp[wave * 4 + q][sub * 8] = o.u;
    }
    __syncthreads();

    // ---- phase 2: MFMA ----
    int row = lane & 15;
    int kl  = (lane >> 4) << 3;
    #pragma unroll
    for (int ks = 0; ks < 4; ++ks)
        A[ks] = *(const bf16x8*)&almp[row][kl + ks * 32];

    f32x4 acc0 = {0.f, 0.f, 0.f, 0.f}, acc1 = {0.f, 0.f, 0.f, 0.f};
    #pragma unroll
    for (int ks = 0; ks < 8; ++ks) {
        acc0 = __builtin_amdgcn_mfma_f32_16x16x32_bf16(A[ks], B[0][ks], acc0, 0, 0, 0);
        acc1 = __builtin_amdgcn_mfma_f32_16x16x32_bf16(A[ks], B[1][ks], acc1, 0, 0, 0);
    }

    // C/D layout: col = lane&15, row = (lane>>4)*4 + reg   [m89-verified]
    int o0   = wave * 32;
    int ocol = lane & 15;
    int rb   = (lane >> 4) << 2;
    float b0 = bias[o0 + ocol];
    float b1 = bias[o0 + 16 + ocol];
    #pragma unroll
    for (int r = 0; r < 4; ++r) {
        size_t n = (size_t)(n0 + rb + r);
        outb[n * DIM + o0 + ocol]      = f2bf(fmaxf(acc0[r] + b0, 0.f));
        outb[n * DIM + o0 + 16 + ocol] = f2bf(fmaxf(acc1[r] + b1, 0.f));
    }
}

// ---------------------------------------------------------------------------
// Pool stage 1: partial per-graph sums (batch sorted; flush on graph change).
// ---------------------------------------------------------------------------
__global__ __launch_bounds__(256) void k_pool_partial(const unsigned short* __restrict__ h2,
                                                      const int* __restrict__ batch,
                                                      float* __restrict__ gsum) {
    int wid  = (blockIdx.x * 256 + threadIdx.x) >> 6;
    int lane = threadIdx.x & 63;
    int n0 = wid * 32;
    if (n0 >= N_NODES) return;
    int n1 = n0 + 32; if (n1 > N_NODES) n1 = N_NODES;
    int col = lane * 2;

    float ax = 0.f, ay = 0.f;
    int cur = batch[n0];
    for (int n = n0; n < n1; ++n) {
        int b = batch[n];
        if (b != cur) {
            atomicAdd(&gsum[cur * DIM + col], ax);
            atomicAdd(&gsum[cur * DIM + col + 1], ay);
            ax = 0.f; ay = 0.f; cur = b;
        }
        unsigned u = *(const unsigned*)(h2 + (size_t)n * DIM + col);
        ax += bflo(u); ay += bfhi(u);
    }
    atomicAdd(&gsum[cur * DIM + col], ax);
    atomicAdd(&gsum[cur * DIM + col + 1], ay);
}

// ---------------------------------------------------------------------------
// Pool stage 2: mean + MLP head. One block per graph.
// ---------------------------------------------------------------------------
__global__ __launch_bounds__(256) void k_head(const float* __restrict__ gsum,
                                              const int* __restrict__ batch,
                                              const float* __restrict__ wl1,
                                              const float* __restrict__ bl1,
                                              const float* __restrict__ wout,
                                              const float* __restrict__ bout,
                                              float* __restrict__ out) {
    int g = blockIdx.x;
    int t = threadIdx.x;

    int lo = 0, hi = N_NODES;
    while (lo < hi) { int mid = (lo + hi) >> 1; if (batch[mid] < g) lo = mid + 1; else hi = mid; }
    int s = lo;
    lo = 0; hi = N_NODES;
    while (lo < hi) { int mid = (lo + hi) >> 1; if (batch[mid] < g + 1) lo = mid + 1; else hi = mid; }
    int e = lo;

    __shared__ float gvec[DIM];
    if (t < DIM) {
        float cnt = fmaxf((float)(e - s), 1.0f);
        gvec[t] = gsum[g * DIM + t] / cnt;
    }
    __syncthreads();
    if (t < 64) {
        float a = bl1[t];
        #pragma unroll 4
        for (int k = 0; k < DIM; ++k) a += wl1[t * DIM + k] * gvec[k];
        float g1 = fmaxf(a, 0.f) * wout[t];
        #pragma unroll
        for (int off = 32; off > 0; off >>= 1) g1 += __shfl_down(g1, off);
        if (t == 0) {
            float z = g1 + bout[0];
            out[g] = 1.0f / (1.0f + expf(-z));
        }
    }
}

// ---------------------------------------------------------------------------
extern "C" void kernel_launch(void* const* d_in, const int* in_sizes, int n_in,
                              void* d_out, int out_size, void* d_ws, size_t ws_size,
                              hipStream_t stream) {
    const float* x     = (const float*)d_in[0];
    const int*   ei    = (const int*)d_in[1];    // int64 in ref -> int32 here
    const int*   batch = (const int*)d_in[2];
    const float* w1l   = (const float*)d_in[3];
    const float* b1l   = (const float*)d_in[4];
    const float* w1r   = (const float*)d_in[5];
    const float* w2l   = (const float*)d_in[6];
    const float* b2l   = (const float*)d_in[7];
    const float* w2r   = (const float*)d_in[8];
    const float* wl1   = (const float*)d_in[9];
    const float* bl1   = (const float*)d_in[10];
    const float* wout  = (const float*)d_in[11];
    const float* bout  = (const float*)d_in[12];
    float* out = (float*)d_out;

    char*  wsp = (char*)d_ws;
    size_t off = 0;
    auto alloc = [&](size_t bytes) -> char* {
        char* p = wsp + off;
        off += (bytes + 255) & ~(size_t)255;
        return p;
    };
    int* rs   = (int*)alloc((size_t)(N_NODES + 1) * 4);
    int* ncur = (int*)alloc((size_t)N_NODES * 4);
    int* hist = (int*)alloc((size_t)N_NODES * 4);
    int* bsum = (int*)alloc(256 * 4);
    int* bcur = (int*)alloc((size_t)NB * BPAD * 4);
    int* srcs = (int*)alloc((size_t)N_EDGES * 4);
    unsigned* tmp = (unsigned*)alloc((size_t)N_EDGES * 4);
    unsigned short* xb    = (unsigned short*)alloc((size_t)N_NODES * DIM * 2);
    unsigned short* h1b   = (unsigned short*)alloc((size_t)N_NODES * DIM * 2);
    unsigned short* h2b   = (unsigned short*)alloc((size_t)N_NODES * DIM * 2);
    unsigned short* wbuf1 = (unsigned short*)alloc((size_t)8 * 8 * 64 * 8 * 2);
    unsigned short* wbuf2 = (unsigned short*)alloc((size_t)8 * 8 * 64 * 8 * 2);
    float* gsum = (float*)alloc((size_t)N_GRAPHS * DIM * 4);

    const int nb = (N_NODES + 511) / 512;   // 98

    hipMemsetAsync(hist, 0, (size_t)N_NODES * 4, stream);
    hipMemsetAsync(gsum, 0, (size_t)N_GRAPHS * DIM * 4, stream);
    k_hist<<<(N_EDGES + 255) / 256, 256, 0, stream>>>(ei, hist);
    k_blocksum<<<nb, 256, 0, stream>>>(hist, bsum);
    k_scan_bsum<<<1, 64, 0, stream>>>(bsum, nb, bcur);
    k_scan_write<<<nb, 512, 0, stream>>>(hist, bsum, rs, ncur);
    k_bucket<<<(N_EDGES + EPB - 1) / EPB, 512, 0, stream>>>(ei, bcur, tmp);
    k_place2<<<NB, 512, 0, stream>>>(tmp, rs, ncur, srcs);

    // dtype prep (single launch: feature convert + both weight packs)
    k_prep<<<(N_NODES * 16 + 2 * 8 * 8 * 64 + 255) / 256, 256, 0, stream>>>(
        x, xb, w1l, w1r, w2l, w2r, wbuf1, wbuf2);

    // conv1 (fused aggregate + GEMM)
    k_sage<<<N_NODES / 16, 256, 0, stream>>>(xb, xb, rs, srcs, wbuf1, b1l, h1b);
    // conv2
    k_sage<<<N_NODES / 16, 256, 0, stream>>>(h1b, h1b, rs, srcs, wbuf2, b2l, h2b);
    // pool (2-stage) + head
    k_pool_partial<<<(N_NODES + 127) / 128, 256, 0, stream>>>(h2b, batch, gsum);
    k_head<<<N_GRAPHS, 256, 0, stream>>>(gsum, batch, wl1, bl1, wout, bout, out);
}

// Round 12
// 219.497 us; speedup vs baseline: 1.1655x; 1.0759x over previous
//
#include <hip/hip_runtime.h>
#include <cstdint>
#include <cstddef>

#define N_NODES  50000
#define N_EDGES  800000
#define DIM      128
#define N_GRAPHS 64
#define NB       98        // coarse buckets of 512 nodes
#define BSH      9
#define EPB      2048      // edges per k_bucket block
#define BPAD     16        // bcur padding: one counter per 64B line

typedef __attribute__((ext_vector_type(8))) short     bf16x8;
typedef __attribute__((ext_vector_type(4))) float     f32x4;

__device__ __forceinline__ int clamp_node(int v) {
    return v < 0 ? 0 : (v >= N_NODES ? N_NODES - 1 : v);
}
__device__ __forceinline__ unsigned short f2bf(float f) {
    union { float f; unsigned u; } v; v.f = f;
    unsigned r = v.u + 0x7FFF + ((v.u >> 16) & 1);   // round-to-nearest-even
    return (unsigned short)(r >> 16);
}
__device__ __forceinline__ float bflo(unsigned u) {
    union { unsigned u; float f; } v; v.u = u << 16; return v.f;
}
__device__ __forceinline__ float bfhi(unsigned u) {
    union { unsigned u; float f; } v; v.u = u & 0xFFFF0000u; return v.f;
}

// ---------------------------------------------------------------------------
// CSR build: histogram of dst, scan. edge_index arrives as int32.
// ---------------------------------------------------------------------------
__global__ void k_hist(const int* __restrict__ ei, int* __restrict__ hist) {
    int e = blockIdx.x * 256 + threadIdx.x;
    if (e < N_EDGES) atomicAdd(&hist[clamp_node(ei[N_EDGES + e])], 1);
}

__global__ void k_blocksum(const int* __restrict__ hist, int* __restrict__ bsum) {
    __shared__ int s[256];
    int base = blockIdx.x * 512;
    int t = threadIdx.x;
    int v = 0;
    if (base + t < N_NODES)       v += hist[base + t];
    if (base + 256 + t < N_NODES) v += hist[base + 256 + t];
    s[t] = v;
    __syncthreads();
    for (int off = 128; off > 0; off >>= 1) {
        if (t < off) s[t] += s[t + off];
        __syncthreads();
    }
    if (t == 0) bsum[blockIdx.x] = s[0];
}

// scan of block sums; also seeds bcur: bucket b's start = rs[b*512] = boff[b].
__global__ void k_scan_bsum(int* bsum, int nb, int* __restrict__ bcur) {
    if (threadIdx.x == 0 && blockIdx.x == 0) {
        int acc = 0;
        for (int i = 0; i < nb; ++i) {
            int v = bsum[i];
            bsum[i] = acc;
            if (i < NB) bcur[i * BPAD] = acc;
            acc += v;
        }
    }
}

// rs[n] = exclusive row start (PRISTINE, never mutated); rs[N]=E. ncur = copy.
__global__ void k_scan_write(const int* __restrict__ hist, const int* __restrict__ boff,
                             int* __restrict__ rs, int* __restrict__ ncur) {
    __shared__ int s[512];
    int t = threadIdx.x;
    int i = blockIdx.x * 512 + t;
    int v = (i < N_NODES) ? hist[i] : 0;
    s[t] = v;
    __syncthreads();
    for (int off = 1; off < 512; off <<= 1) {
        int y = (t >= off) ? s[t - off] : 0;
        __syncthreads();
        s[t] += y;
        __syncthreads();
    }
    int base = boff[blockIdx.x];
    if (i < N_NODES) {
        int st = base + s[t] - v;
        rs[i] = st; ncur[i] = st;
    }
    if (i == N_NODES - 1) rs[N_NODES] = base + s[t];
}

// ---------------------------------------------------------------------------
// Placement phase A: 391 blocks x 2048 edges; LDS counting sort into 98
// coarse buckets; bulk-append runs to global bucket regions. bcur line-padded
// + blockIdx-staggered flush (round-7 lesson: same-line cursor convoy).
// Packed entry: src (16b) | dst_local (9b) << 16.
// ---------------------------------------------------------------------------
__global__ __launch_bounds__(512) void k_bucket(const int* __restrict__ ei,
                                                int* __restrict__ bcur,
                                                unsigned* __restrict__ tmp) {
    __shared__ int cnt[128], cur[128], ofs[128];
    __shared__ int s[512];
    __shared__ unsigned list[EPB];
    int t = threadIdx.x;
    int base = blockIdx.x * EPB;
    int eend = base + EPB; if (eend > N_EDGES) eend = N_EDGES;

    if (t < 128) cnt[t] = 0;
    __syncthreads();

    int d[4], sv[4];
    bool ok[4];
    #pragma unroll
    for (int i = 0; i < 4; ++i) {
        int e = base + t + i * 512;
        ok[i] = (e < eend);
        if (ok[i]) {
            d[i]  = clamp_node(ei[N_EDGES + e]);
            sv[i] = clamp_node(ei[e]);
            atomicAdd(&cnt[d[i] >> BSH], 1);
        }
    }
    __syncthreads();
    int v = (t < 128) ? cnt[t] : 0;
    s[t] = v;
    __syncthreads();
    for (int off = 1; off < 128; off <<= 1) {
        int y = (t >= off && t < 128) ? s[t - off] : 0;
        __syncthreads();
        if (t < 128) s[t] += y;
        __syncthreads();
    }
    if (t < 128) { ofs[t] = s[t] - v; cur[t] = s[t] - v; }
    __syncthreads();
    #pragma unroll
    for (int i = 0; i < 4; ++i) {
        if (ok[i]) {
            int b = d[i] >> BSH;
            int p = atomicAdd(&cur[b], 1);
            list[p] = (unsigned)sv[i] | ((unsigned)(d[i] & 511) << 16);
        }
    }
    __syncthreads();
    int wv = t >> 6, lane = t & 63;
    const int NGRP = 13;   // ceil(98/8)
    for (int jj = 0; jj < NGRP; ++jj) {
        int b = wv + 8 * ((jj + (int)blockIdx.x) % NGRP);
        if (b >= NB) continue;
        int c = cnt[b];
        if (c == 0) continue;
        int gpos;
        if (lane == 0) gpos = atomicAdd(&bcur[b * BPAD], c);
        gpos = __shfl(gpos, 0);
        int ls = ofs[b];
        for (int i = lane; i < c; i += 64) tmp[gpos + i] = list[ls + i];
    }
}

// ---------------------------------------------------------------------------
// Placement phase B: one block per bucket; scatter confined to the
// block-exclusive 32KB srcs region (full-line evicts).
// ---------------------------------------------------------------------------
__global__ __launch_bounds__(512) void k_place2(const unsigned* __restrict__ tmp,
                                                const int* __restrict__ rs,
                                                int* __restrict__ ncur,
                                                int* __restrict__ srcs) {
    int b   = blockIdx.x;
    int nlo = b << BSH;
    int nhi = nlo + 512; if (nhi > N_NODES) nhi = N_NODES;
    int estart = rs[nlo], eend = rs[nhi];
    for (int e = estart + (int)threadIdx.x; e < eend; e += 512) {
        unsigned val = tmp[e];
        int d = nlo + (int)(val >> 16);
        int pos = atomicAdd(&ncur[d], 1);
        srcs[pos] = (int)(val & 0xFFFFu);
    }
}

// ---------------------------------------------------------------------------
// Prep (one launch): f32->bf16 row-major feature convert + pack both concat
// weights [Wl;Wr]^T into MFMA fragment order.
// frag[(ot*8+ks)*64 + lane][j] = B[ks*32 + (lane>>4)*8 + j][ot*16 + (lane&15)]
// ---------------------------------------------------------------------------
__global__ __launch_bounds__(256) void k_prep(const float* __restrict__ x,
                                              unsigned short* __restrict__ xb,
                                              const float* __restrict__ W1l,
                                              const float* __restrict__ W1r,
                                              const float* __restrict__ W2l,
                                              const float* __restrict__ W2r,
                                              unsigned short* __restrict__ wbuf1,
                                              unsigned short* __restrict__ wbuf2) {
    int i = blockIdx.x * 256 + threadIdx.x;
    const int n8 = N_NODES * 16;            // 800000 8-elem conversions
    if (i < n8) {
        const float4* p = (const float4*)(x + (size_t)i * 8);
        float4 a = p[0], b = p[1];
        union { unsigned short s[8]; uint4 u; } o;
        o.s[0] = f2bf(a.x); o.s[1] = f2bf(a.y); o.s[2] = f2bf(a.z); o.s[3] = f2bf(a.w);
        o.s[4] = f2bf(b.x); o.s[5] = f2bf(b.y); o.s[6] = f2bf(b.z); o.s[7] = f2bf(b.w);
        *(uint4*)(xb + (size_t)i * 8) = o.u;
        return;
    }
    int tid = i - n8;
    if (tid >= 2 * 8 * 8 * 64) return;
    int which = tid >> 12;
    int id    = tid & 4095;
    const float* Wl = which ? W2l : W1l;
    const float* Wr = which ? W2r : W1r;
    unsigned short* wbuf = which ? wbuf2 : wbuf1;
    int lane = id & 63;
    int ks   = (id >> 6) & 7;
    int ot   = id >> 9;
    int o  = ot * 16 + (lane & 15);
    int kb = ks * 32 + ((lane >> 4) << 3);
    union { unsigned short s[8]; uint4 u; } frag;
    #pragma unroll
    for (int j = 0; j < 8; ++j) {
        int k = kb + j;
        float v = (k < DIM) ? Wl[o * DIM + k] : Wr[o * DIM + (k - DIM)];
        frag.s[j] = f2bf(v);
    }
    *(uint4*)(wbuf + (size_t)id * 8) = frag.u;
}

// ---------------------------------------------------------------------------
// FUSED SAGE layer (round-9 proven form): gather-mean (4 nodes/wave, 8x
// unroll) -> LDS tile -> MFMA dual-GEMM + bias + ReLU -> bf16 store.
// Block = 4 waves = 16 nodes. B-fragments before the gather; root A-frags
// AFTER the barrier (round-11 lesson: preloading them costs 8 VGPR ->
// occupancy 24.6->17.9% -> k_sage +8us. Register headroom beats manual
// prefetch in the latency-bound gather phase).
// Round-10 lesson: per-block dim-chunking desyncs across blocks; don't chunk.
// ---------------------------------------------------------------------------
__global__ __launch_bounds__(256) void k_sage(const unsigned short* __restrict__ feat,
                                              const unsigned short* __restrict__ in2b,
                                              const int* __restrict__ rs,
                                              const int* __restrict__ srcs,
                                              const unsigned short* __restrict__ wbuf,
                                              const float* __restrict__ bias,
                                              unsigned short* __restrict__ outb) {
    __shared__ unsigned short almp[16][136];   // row stride 272B
    int t    = threadIdx.x;
    int wave = t >> 6;
    int lane = t & 63;
    int n0   = blockIdx.x * 16;

    // B fragments (independent; scheduler hides them under the gather)
    bf16x8 B[2][8];
    #pragma unroll
    for (int ot = 0; ot < 2; ++ot)
        #pragma unroll
        for (int ks = 0; ks < 8; ++ks)
            B[ot][ks] = *(const bf16x8*)(wbuf +
                (((size_t)(wave * 2 + ot) * 8 + ks) * 64 + lane) * 8);

    // ---- phase 1: gather-mean; lane (q,sub) owns node q's 16B chunk sub ----
    {
        int q   = lane >> 4;
        int sub = lane & 15;
        int node  = n0 + wave * 4 + q;
        int start = rs[node];
        int end   = rs[node + 1];
        float a0 = 0.f, a1 = 0.f, a2 = 0.f, a3 = 0.f;
        float a4 = 0.f, a5 = 0.f, a6 = 0.f, a7 = 0.f;
        const size_t coff = (size_t)sub * 8;

#define ACC8(r) { a0 += bflo(r.x); a1 += bfhi(r.x); a2 += bflo(r.y); a3 += bfhi(r.y); \
                  a4 += bflo(r.z); a5 += bfhi(r.z); a6 += bflo(r.w); a7 += bfhi(r.w); }
        int e = start;
        for (; e + 8 <= end; e += 8) {
            uint4 r0 = *(const uint4*)(feat + (size_t)srcs[e + 0] * DIM + coff);
            uint4 r1 = *(const uint4*)(feat + (size_t)srcs[e + 1] * DIM + coff);
            uint4 r2 = *(const uint4*)(feat + (size_t)srcs[e + 2] * DIM + coff);
            uint4 r3 = *(const uint4*)(feat + (size_t)srcs[e + 3] * DIM + coff);
            uint4 r4 = *(const uint4*)(feat + (size_t)srcs[e + 4] * DIM + coff);
            uint4 r5 = *(const uint4*)(feat + (size_t)srcs[e + 5] * DIM + coff);
            uint4 r6 = *(const uint4*)(feat + (size_t)srcs[e + 6] * DIM + coff);
            uint4 r7 = *(const uint4*)(feat + (size_t)srcs[e + 7] * DIM + coff);
            ACC8(r0) ACC8(r1) ACC8(r2) ACC8(r3) ACC8(r4) ACC8(r5) ACC8(r6) ACC8(r7)
        }
        for (; e + 2 <= end; e += 2) {
            uint4 r0 = *(const uint4*)(feat + (size_t)srcs[e + 0] * DIM + coff);
            uint4 r1 = *(const uint4*)(feat + (size_t)srcs[e + 1] * DIM + coff);
            ACC8(r0) ACC8(r1)
        }
        if (e < end) {
            uint4 r0 = *(const uint4*)(feat + (size_t)srcs[e] * DIM + coff);
            ACC8(r0)
        }
#undef ACC8
        float inv = 1.0f / fmaxf((float)(end - start), 1.0f);
        union { unsigned short s[8]; uint4 u; } o;
        o.s[0] = f2bf(a0 * inv); o.s[1] = f2bf(a1 * inv);
        o.s[2] = f2bf(a2 * inv); o.s[3] = f2bf(a3 * inv);
        o.s[4] = f2bf(a4 * inv); o.s[5] = f2bf(a5 * inv);
        o.s[6] = f2bf(a6 * inv); o.s[7] = f2bf(a7 * inv);
        *(uint4*)&almp[wave * 4 + q][sub * 8] = o.u;
    }
    __syncthreads();

    // ---- phase 2: MFMA ----
    int row = lane & 15;
    int kl  = (lane >> 4) << 3;
    bf16x8 A[8];
    #pragma unroll
    for (int ks = 0; ks < 4; ++ks)
        A[ks] = *(const bf16x8*)&almp[row][kl + ks * 32];
    const unsigned short* xrow = in2b + (size_t)(n0 + row) * DIM + kl;
    #pragma unroll
    for (int ks = 0; ks < 4; ++ks)
        A[4 + ks] = *(const bf16x8*)(xrow + ks * 32);

    f32x4 acc0 = {0.f, 0.f, 0.f, 0.f}, acc1 = {0.f, 0.f, 0.f, 0.f};
    #pragma unroll
    for (int ks = 0; ks < 8; ++ks) {
        acc0 = __builtin_amdgcn_mfma_f32_16x16x32_bf16(A[ks], B[0][ks], acc0, 0, 0, 0);
        acc1 = __builtin_amdgcn_mfma_f32_16x16x32_bf16(A[ks], B[1][ks], acc1, 0, 0, 0);
    }

    // C/D layout: col = lane&15, row = (lane>>4)*4 + reg   [m89-verified]
    int o0   = wave * 32;
    int ocol = lane & 15;
    int rb   = (lane >> 4) << 2;
    float b0 = bias[o0 + ocol];
    float b1 = bias[o0 + 16 + ocol];
    #pragma unroll
    for (int r = 0; r < 4; ++r) {
        size_t n = (size_t)(n0 + rb + r);
        outb[n * DIM + o0 + ocol]      = f2bf(fmaxf(acc0[r] + b0, 0.f));
        outb[n * DIM + o0 + 16 + ocol] = f2bf(fmaxf(acc1[r] + b1, 0.f));
    }
}

// ---------------------------------------------------------------------------
// Pool stage 1: partial per-graph sums (batch sorted; flush on graph change).
// ---------------------------------------------------------------------------
__global__ __launch_bounds__(256) void k_pool_partial(const unsigned short* __restrict__ h2,
                                                      const int* __restrict__ batch,
                                                      float* __restrict__ gsum) {
    int wid  = (blockIdx.x * 256 + threadIdx.x) >> 6;
    int lane = threadIdx.x & 63;
    int n0 = wid * 32;
    if (n0 >= N_NODES) return;
    int n1 = n0 + 32; if (n1 > N_NODES) n1 = N_NODES;
    int col = lane * 2;

    float ax = 0.f, ay = 0.f;
    int cur = batch[n0];
    for (int n = n0; n < n1; ++n) {
        int b = batch[n];
        if (b != cur) {
            atomicAdd(&gsum[cur * DIM + col], ax);
            atomicAdd(&gsum[cur * DIM + col + 1], ay);
            ax = 0.f; ay = 0.f; cur = b;
        }
        unsigned u = *(const unsigned*)(h2 + (size_t)n * DIM + col);
        ax += bflo(u); ay += bfhi(u);
    }
    atomicAdd(&gsum[cur * DIM + col], ax);
    atomicAdd(&gsum[cur * DIM + col + 1], ay);
}

// ---------------------------------------------------------------------------
// Pool stage 2: mean + MLP head. One block per graph.
// ---------------------------------------------------------------------------
__global__ __launch_bounds__(256) void k_head(const float* __restrict__ gsum,
                                              const int* __restrict__ batch,
                                              const float* __restrict__ wl1,
                                              const float* __restrict__ bl1,
                                              const float* __restrict__ wout,
                                              const float* __restrict__ bout,
                                              float* __restrict__ out) {
    int g = blockIdx.x;
    int t = threadIdx.x;

    int lo = 0, hi = N_NODES;
    while (lo < hi) { int mid = (lo + hi) >> 1; if (batch[mid] < g) lo = mid + 1; else hi = mid; }
    int s = lo;
    lo = 0; hi = N_NODES;
    while (lo < hi) { int mid = (lo + hi) >> 1; if (batch[mid] < g + 1) lo = mid + 1; else hi = mid; }
    int e = lo;

    __shared__ float gvec[DIM];
    if (t < DIM) {
        float cnt = fmaxf((float)(e - s), 1.0f);
        gvec[t] = gsum[g * DIM + t] / cnt;
    }
    __syncthreads();
    if (t < 64) {
        float a = bl1[t];
        #pragma unroll 4
        for (int k = 0; k < DIM; ++k) a += wl1[t * DIM + k] * gvec[k];
        float g1 = fmaxf(a, 0.f) * wout[t];
        #pragma unroll
        for (int off = 32; off > 0; off >>= 1) g1 += __shfl_down(g1, off);
        if (t == 0) {
            float z = g1 + bout[0];
            out[g] = 1.0f / (1.0f + expf(-z));
        }
    }
}

// ---------------------------------------------------------------------------
extern "C" void kernel_launch(void* const* d_in, const int* in_sizes, int n_in,
                              void* d_out, int out_size, void* d_ws, size_t ws_size,
                              hipStream_t stream) {
    const float* x     = (const float*)d_in[0];
    const int*   ei    = (const int*)d_in[1];    // int64 in ref -> int32 here
    const int*   batch = (const int*)d_in[2];
    const float* w1l   = (const float*)d_in[3];
    const float* b1l   = (const float*)d_in[4];
    const float* w1r   = (const float*)d_in[5];
    const float* w2l   = (const float*)d_in[6];
    const float* b2l   = (const float*)d_in[7];
    const float* w2r   = (const float*)d_in[8];
    const float* wl1   = (const float*)d_in[9];
    const float* bl1   = (const float*)d_in[10];
    const float* wout  = (const float*)d_in[11];
    const float* bout  = (const float*)d_in[12];
    float* out = (float*)d_out;

    char*  wsp = (char*)d_ws;
    size_t off = 0;
    auto alloc = [&](size_t bytes) -> char* {
        char* p = wsp + off;
        off += (bytes + 255) & ~(size_t)255;
        return p;
    };
    int* rs   = (int*)alloc((size_t)(N_NODES + 1) * 4);
    int* ncur = (int*)alloc((size_t)N_NODES * 4);
    int* hist = (int*)alloc((size_t)N_NODES * 4);
    int* bsum = (int*)alloc(256 * 4);
    int* bcur = (int*)alloc((size_t)NB * BPAD * 4);
    int* srcs = (int*)alloc((size_t)N_EDGES * 4);
    unsigned* tmp = (unsigned*)alloc((size_t)N_EDGES * 4);
    unsigned short* xb    = (unsigned short*)alloc((size_t)N_NODES * DIM * 2);
    unsigned short* h1b   = (unsigned short*)alloc((size_t)N_NODES * DIM * 2);
    unsigned short* h2b   = (unsigned short*)alloc((size_t)N_NODES * DIM * 2);
    unsigned short* wbuf1 = (unsigned short*)alloc((size_t)8 * 8 * 64 * 8 * 2);
    unsigned short* wbuf2 = (unsigned short*)alloc((size_t)8 * 8 * 64 * 8 * 2);
    float* gsum = (float*)alloc((size_t)N_GRAPHS * DIM * 4);

    const int nb = (N_NODES + 511) / 512;   // 98

    hipMemsetAsync(hist, 0, (size_t)N_NODES * 4, stream);
    hipMemsetAsync(gsum, 0, (size_t)N_GRAPHS * DIM * 4, stream);
    k_hist<<<(N_EDGES + 255) / 256, 256, 0, stream>>>(ei, hist);
    k_blocksum<<<nb, 256, 0, stream>>>(hist, bsum);
    k_scan_bsum<<<1, 64, 0, stream>>>(bsum, nb, bcur);
    k_scan_write<<<nb, 512, 0, stream>>>(hist, bsum, rs, ncur);
    k_bucket<<<(N_EDGES + EPB - 1) / EPB, 512, 0, stream>>>(ei, bcur, tmp);
    k_place2<<<NB, 512, 0, stream>>>(tmp, rs, ncur, srcs);

    // dtype prep (single launch: feature convert + both weight packs)
    k_prep<<<(N_NODES * 16 + 2 * 8 * 8 * 64 + 255) / 256, 256, 0, stream>>>(
        x, xb, w1l, w1r, w2l, w2r, wbuf1, wbuf2);

    // conv1 (fused aggregate + GEMM)
    k_sage<<<N_NODES / 16, 256, 0, stream>>>(xb, xb, rs, srcs, wbuf1, b1l, h1b);
    // conv2
    k_sage<<<N_NODES / 16, 256, 0, stream>>>(h1b, h1b, rs, srcs, wbuf2, b2l, h2b);
    // pool (2-stage) + head
    k_pool_partial<<<(N_NODES + 127) / 128, 256, 0, stream>>>(h2b, batch, gsum);
    k_head<<<N_GRAPHS, 256, 0, stream>>>(gsum, batch, wl1, bl1, wout, bout, out);
}